// Round 4
// baseline (652.842 us; speedup 1.0000x reference)
//
#include <hip/hip_runtime.h>
#include <math.h>

#define B_ 4096
#define D_ 512
#define G_ 128
#define N_ (G_*G_)        // 16384
#define NT 128            // number of 128-wide n tiles
#define THR_ 0.95f
#define IMAX_ 0x7FFFFFFF

typedef float f32x4 __attribute__((ext_vector_type(4)));
typedef _Float16 half8 __attribute__((ext_vector_type(8)));

// ---------------- split fp32 -> f16 hi + f16 lo (A only) ----------------
__global__ __launch_bounds__(256) void split_kernel(const float* __restrict__ src,
                                                    _Float16* __restrict__ hi,
                                                    _Float16* __restrict__ lo, int n4) {
    int i = blockIdx.x * 256 + threadIdx.x;
    if (i >= n4) return;
    float4 v = ((const float4*)src)[i];
    float vv[4] = {v.x, v.y, v.z, v.w};
    union { _Float16 h[4]; uint64_t u64; } H, L;
    #pragma unroll
    for (int j = 0; j < 4; j++) {
        _Float16 h = (_Float16)vv[j];
        H.h[j] = h;
        L.h[j] = (_Float16)(vv[j] - (float)h);
    }
    ((uint64_t*)hi)[i] = H.u64;
    ((uint64_t*)lo)[i] = L.u64;
}

// ---------------- fused W split + wnorm ----------------
__global__ __launch_bounds__(64) void prep_w_kernel(const float* __restrict__ W,
                                                    _Float16* __restrict__ hi,
                                                    _Float16* __restrict__ lo,
                                                    float* __restrict__ wnorm) {
    int n = blockIdx.x, t = threadIdx.x;
    const float* row = W + (size_t)n * D_;
    float4 a = ((const float4*)row)[t];
    float4 b = ((const float4*)row)[t + 64];
    float av[4] = {a.x, a.y, a.z, a.w}, bv[4] = {b.x, b.y, b.z, b.w};
    union { _Float16 h[4]; uint64_t u64; } Ha, La, Hb, Lb;
    #pragma unroll
    for (int j = 0; j < 4; j++) {
        _Float16 h = (_Float16)av[j]; Ha.h[j] = h; La.h[j] = (_Float16)(av[j] - (float)h);
        _Float16 g = (_Float16)bv[j]; Hb.h[j] = g; Lb.h[j] = (_Float16)(bv[j] - (float)g);
    }
    ((uint64_t*)(hi + (size_t)n * D_))[t]       = Ha.u64;
    ((uint64_t*)(hi + (size_t)n * D_ + 256))[t] = Hb.u64;
    ((uint64_t*)(lo + (size_t)n * D_))[t]       = La.u64;
    ((uint64_t*)(lo + (size_t)n * D_ + 256))[t] = Lb.u64;
    float s = a.x*a.x + a.y*a.y + a.z*a.z + a.w*a.w
            + b.x*b.x + b.y*b.y + b.z*b.z + b.w*b.w;
    #pragma unroll
    for (int off = 32; off > 0; off >>= 1) s += __shfl_down(s, off, 64);
    if (t == 0) wnorm[n] = s;
}

// ---------------- MFMA score GEMM: 3 passes per staged W-chunk ----------------
// dot(x,w) = xhi.whi + xhi.wlo + xlo.whi.  Per K=32 chunk: stage {Whi,Wlo} to
// LDS once (dbuf), keep A-frags in registers (ah dbuf-prefetch, al early-load),
// run 48 MFMA. XOR-swizzled staging: lane loads source chunk (lane&3)^((lane>>3)&3)
// so reads at pos quad^((c>>1)&3) are 2-way bank-aliased (free) instead of 8-way.
__global__ __launch_bounds__(256) void score_mfma_kernel(
    const _Float16* __restrict__ Ahi, const _Float16* __restrict__ Alo,
    const _Float16* __restrict__ Whi, const _Float16* __restrict__ Wlo,
    const float* __restrict__ wnorm,
    const int* __restrict__ labels, const int* __restrict__ clabels,
    float* __restrict__ pminv, int* __restrict__ pmini,
    float* __restrict__ pcminv, int* __restrict__ pcmini)
{
    __shared__ __align__(16) char smem[32768];   // 2 x (Wh 8KB + Wl 8KB)

    const int tid  = threadIdx.x;
    const int lane = tid & 63;
    const int wave = tid >> 6;
    const int wm = wave >> 1, wn = wave & 1;   // 2x2 wave grid, 64x64 per wave
    const int m0 = blockIdx.y * 128;
    const int n0 = blockIdx.x * 128;
    const int c = lane & 15, quad = lane >> 4;

    // W staging offsets (source k-chunk XOR-swizzled; LDS dest = lane-contiguous)
    unsigned offW[2]; int offL[2];
    {
        int srow = wave * 16 + (lane >> 2);
        int sq = ((lane & 3) ^ ((lane >> 3) & 3)) * 8;
        #pragma unroll
        for (int r2 = 0; r2 < 2; r2++) {
            int row = r2 * 64 + srow;              // 0..127, each exactly once
            offW[r2] = (unsigned)(n0 + row) * D_ + sq;
            offL[r2] = row * 32 + (lane & 3) * 8;  // byte = waveBase + lane*16
        }
    }
    // A fragment source offsets (row-gather, L2-resident)
    unsigned offA[4];
    #pragma unroll
    for (int i = 0; i < 4; i++)
        offA[i] = (unsigned)(m0 + wm * 64 + i * 16 + c) * D_ + quad * 8;

    const int rpos = (quad ^ ((c >> 1) & 3)) * 8;  // reader swizzled chunk (elements)

    f32x4 acc[4][4];
    #pragma unroll
    for (int i = 0; i < 4; i++)
        #pragma unroll
        for (int j = 0; j < 4; j++)
            acc[i][j] = (f32x4){0.f, 0.f, 0.f, 0.f};

    // prologue: stage chunk 0 into buf 0; prefetch ah chunk 0
    {
        _Float16* Wh = (_Float16*)smem;
        _Float16* Wl = (_Float16*)(smem + 8192);
        #pragma unroll
        for (int r2 = 0; r2 < 2; r2++) {
            __builtin_amdgcn_global_load_lds(
                (const __attribute__((address_space(1))) void*)(Whi + offW[r2]),
                (__attribute__((address_space(3))) void*)(Wh + offL[r2]), 16, 0, 0);
            __builtin_amdgcn_global_load_lds(
                (const __attribute__((address_space(1))) void*)(Wlo + offW[r2]),
                (__attribute__((address_space(3))) void*)(Wl + offL[r2]), 16, 0, 0);
        }
    }
    half8 ah[2][4];
    #pragma unroll
    for (int i = 0; i < 4; i++) ah[0][i] = *(const half8*)(Ahi + offA[i]);

    #pragma unroll
    for (int t = 0; t < 16; t++) {
        const int p = t & 1, np = p ^ 1;
        __syncthreads();   // publishes buf p (vmcnt drain has ~1 full iter slack)
        if (t < 15) {
            const int k1 = (t + 1) * 32;
            _Float16* Wh = (_Float16*)(smem + (np << 14));
            _Float16* Wl = (_Float16*)(smem + (np << 14) + 8192);
            #pragma unroll
            for (int r2 = 0; r2 < 2; r2++) {
                __builtin_amdgcn_global_load_lds(
                    (const __attribute__((address_space(1))) void*)(Whi + offW[r2] + k1),
                    (__attribute__((address_space(3))) void*)(Wh + offL[r2]), 16, 0, 0);
                __builtin_amdgcn_global_load_lds(
                    (const __attribute__((address_space(1))) void*)(Wlo + offW[r2] + k1),
                    (__attribute__((address_space(3))) void*)(Wl + offL[r2]), 16, 0, 0);
            }
            #pragma unroll
            for (int i = 0; i < 4; i++)
                ah[np][i] = *(const half8*)(Ahi + offA[i] + k1);
        }
        // A-lo frags for this chunk — consumed only in pass 3 (long slack)
        half8 al[4];
        {
            const int k0 = t * 32;
            #pragma unroll
            for (int i = 0; i < 4; i++)
                al[i] = *(const half8*)(Alo + offA[i] + k0);
        }

        const _Float16* Wh = (const _Float16*)(smem + (p << 14));
        const _Float16* Wl = (const _Float16*)(smem + (p << 14) + 8192);
        half8 bh[4];
        #pragma unroll
        for (int j = 0; j < 4; j++)
            bh[j] = *(const half8*)&Wh[(wn * 64 + j * 16 + c) * 32 + rpos];
        // pass 1: hi*hi
        #pragma unroll
        for (int i = 0; i < 4; i++)
            #pragma unroll
            for (int j = 0; j < 4; j++)
                acc[i][j] = __builtin_amdgcn_mfma_f32_16x16x32_f16(ah[p][i], bh[j], acc[i][j], 0, 0, 0);
        // pass 2: hi*lo
        half8 bl[4];
        #pragma unroll
        for (int j = 0; j < 4; j++)
            bl[j] = *(const half8*)&Wl[(wn * 64 + j * 16 + c) * 32 + rpos];
        #pragma unroll
        for (int i = 0; i < 4; i++)
            #pragma unroll
            for (int j = 0; j < 4; j++)
                acc[i][j] = __builtin_amdgcn_mfma_f32_16x16x32_f16(ah[p][i], bl[j], acc[i][j], 0, 0, 0);
        // pass 3: lo*hi
        #pragma unroll
        for (int i = 0; i < 4; i++)
            #pragma unroll
            for (int j = 0; j < 4; j++)
                acc[i][j] = __builtin_amdgcn_mfma_f32_16x16x32_f16(al[i], bh[j], acc[i][j], 0, 0, 0);
    }
    __syncthreads();   // done with W tiles; reuse smem for reduction staging

    // per-lane epilogue: score s = wnorm[n] - 2*acc; argmin over (ni, c)
    float wnl[4]; int cll[4];
    #pragma unroll
    for (int ni = 0; ni < 4; ni++) {
        int n = n0 + wn * 64 + ni * 16 + c;
        wnl[ni] = wnorm[n];
        cll[ni] = clabels[n];
    }

    float* redv = (float*)smem;                 // [2][128]
    int*   redi = (int*)(smem + 1024);          // [2][128]
    float* rcv  = (float*)(smem + 2048);        // [2][128]
    int*   rci  = (int*)(smem + 3072);          // [2][128]

    #pragma unroll
    for (int mi = 0; mi < 4; mi++) {
        #pragma unroll
        for (int r = 0; r < 4; r++) {
            int rowg = wm * 64 + mi * 16 + quad * 4 + r;   // 0..127 in block
            int lb = labels[m0 + rowg];
            float bv = INFINITY; int bn = IMAX_;
            float cv = INFINITY; int cn = IMAX_;
            #pragma unroll
            for (int ni = 0; ni < 4; ni++) {
                float s = fmaf(-2.f, acc[mi][ni][r], wnl[ni]);
                int n = n0 + wn * 64 + ni * 16 + c;
                if (s < bv || (s == bv && n < bn)) { bv = s; bn = n; }
                float cs = (cll[ni] == lb) ? s : INFINITY;
                if (cs < cv || (cs == cv && n < cn)) { cv = cs; cn = n; }
            }
            #pragma unroll
            for (int off = 1; off < 16; off <<= 1) {   // butterfly over c
                float ov = __shfl_xor(bv, off, 64); int on = __shfl_xor(bn, off, 64);
                if (ov < bv || (ov == bv && on < bn)) { bv = ov; bn = on; }
                float ocv = __shfl_xor(cv, off, 64); int ocn = __shfl_xor(cn, off, 64);
                if (ocv < cv || (ocv == cv && ocn < cn)) { cv = ocv; cn = ocn; }
            }
            if (c == 0) {
                redv[wn * 128 + rowg] = bv; redi[wn * 128 + rowg] = bn;
                rcv [wn * 128 + rowg] = cv; rci [wn * 128 + rowg] = cn;
            }
        }
    }
    __syncthreads();
    if (tid < 128) {
        float bv = redv[tid];      int bn = redi[tid];
        float ov = redv[128 + tid]; int on = redi[128 + tid];
        if (ov < bv || (ov == bv && on < bn)) { bv = ov; bn = on; }
        float cv = rcv[tid];       int cn = rci[tid];
        float ocv = rcv[128 + tid]; int ocn = rci[128 + tid];
        if (ocv < cv || (ocv == cv && ocn < cn)) { cv = ocv; cn = ocn; }
        size_t pp = (size_t)(m0 + tid) * NT + blockIdx.x;
        pminv[pp] = bv; pmini[pp] = bn; pcminv[pp] = cv; pcmini[pp] = cn;
    }
}

// ---------------- reduce partials per row; emit bmu, sum(min_dists), som_errors,
// and fused per-BMU scatter (S[bmu] += A[b], count[bmu] += 1) ----------------
__global__ __launch_bounds__(128) void reduce_kernel(
    const float* __restrict__ A, const float* __restrict__ W,
    const float* __restrict__ crel,
    const float* __restrict__ pminv, const int* __restrict__ pmini,
    const float* __restrict__ pcminv, const int* __restrict__ pcmini,
    float* __restrict__ sum_min, float* __restrict__ out0,
    float* S, float* count)
{
    int b = blockIdx.x, t = threadIdx.x;
    __shared__ float sv[128]; __shared__ int si[128];
    __shared__ float scv[128]; __shared__ int sci[128];
    __shared__ float xs[128];
    __shared__ int   cbmu_s, bmu_s;

    size_t p = (size_t)b * NT + t;
    sv[t] = pminv[p]; si[t] = pmini[p]; scv[t] = pcminv[p]; sci[t] = pcmini[p];

    float4 x4 = ((const float4*)(A + (size_t)b * D_))[t];
    xs[t] = x4.x*x4.x + x4.y*x4.y + x4.z*x4.z + x4.w*x4.w;
    __syncthreads();
    for (int s = 64; s > 0; s >>= 1) {
        if (t < s) {
            float v = sv[t+s]; int idx = si[t+s];
            if (v < sv[t] || (v == sv[t] && idx < si[t])) { sv[t] = v; si[t] = idx; }
            v = scv[t+s]; idx = sci[t+s];
            if (v < scv[t] || (v == scv[t] && idx < sci[t])) { scv[t] = v; sci[t] = idx; }
            xs[t] += xs[t+s];
        }
        __syncthreads();
    }
    if (t == 0) {
        bmu_s = si[0];
        float md = xs[0] + sv[0];
        if (md < 0.f) md = 0.f;
        atomicAdd(sum_min, md);
        cbmu_s = sci[0];
        atomicAdd(&count[si[0]], 1.0f);
    }
    __syncthreads();
    // som_errors
    int cb = cbmu_s;
    float r = crel[cb] / 100.0f;
    float val = (r >= THR_) ? 1.0f : 0.0f;
    float sc = 0.01f * r * val;
    float4 w4 = ((const float4*)(W + (size_t)cb * D_))[t];
    float4 o;
    o.x = sc * (w4.x - x4.x); o.y = sc * (w4.y - x4.y);
    o.z = sc * (w4.z - x4.z); o.w = sc * (w4.w - x4.w);
    ((float4*)(out0 + (size_t)b * D_))[t] = o;
    // fused scatter
    int bm = bmu_s;
    float* Sp = S + (size_t)bm * D_ + t * 4;
    atomicAdd(Sp + 0, x4.x); atomicAdd(Sp + 1, x4.y);
    atomicAdd(Sp + 2, x4.z); atomicAdd(Sp + 3, x4.w);
}

// ---------------- denom via Chebyshev stencil over counts ----------------
__global__ __launch_bounds__(256) void denom_kernel(
    const float* __restrict__ count,
    const int* __restrict__ epoch_p, const int* __restrict__ maxep_p,
    float* __restrict__ denom)
{
    int n = blockIdx.x * 256 + threadIdx.x;
    if (n >= N_) return;
    int ep = epoch_p[0], me = maxep_p[0];
    float progress = (me > 0) ? (float)(me - ep) / (float)me : 0.f;
    progress = fminf(fmaxf(progress, 0.f), 1.f);
    float p2 = progress * progress;
    int ctx = (int)(p2 * p2 * 2.0f);
    float lr = 0.05f + progress * 0.15f;

    int i = n / G_, j = n % G_;
    float s = 0.f;
    for (int di = -ctx; di <= ctx; di++) {
        int ia = i - di; if (ia < 0 || ia >= G_) continue;
        for (int dj = -ctx; dj <= ctx; dj++) {
            int jb = j - dj; if (jb < 0 || jb >= G_) continue;
            int ad = abs(di), aj = abs(dj);
            int cheb = ad > aj ? ad : aj;
            s += ldexpf(lr, -cheb) * count[jb * G_ + ia];
        }
    }
    denom[n] = s;
}

// ---------------- final: out1 = som + stencil(S) - som*denom (gated) ----------------
__global__ __launch_bounds__(256) void final_kernel(
    const float* __restrict__ som, const float* __restrict__ S,
    const float* __restrict__ denom, const float* __restrict__ sum_min,
    const int* __restrict__ epoch_p, const int* __restrict__ maxep_p,
    float* __restrict__ out1)
{
    size_t i4 = (size_t)blockIdx.x * 256 + threadIdx.x;
    if (i4 >= (size_t)N_ * D_ / 4) return;
    int n = (int)(i4 >> 7);          // 128 float4 per cell row
    int d4 = (int)(i4 & 127);
    float4 s = ((const float4*)som)[i4];
    bool gate = sum_min[0] > 1e-4f * (float)B_;   // mean(min_dists) > 1e-4
    float4 o = s;
    if (gate) {
        int ep = epoch_p[0], me = maxep_p[0];
        float progress = (me > 0) ? (float)(me - ep) / (float)me : 0.f;
        progress = fminf(fmaxf(progress, 0.f), 1.f);
        float p2 = progress * progress;
        int ctx = (int)(p2 * p2 * 2.0f);
        float lr = 0.05f + progress * 0.15f;

        int i = n / G_, j = n % G_;
        float4 nu = {0.f, 0.f, 0.f, 0.f};
        for (int di = -ctx; di <= ctx; di++) {
            int ia = i - di; if (ia < 0 || ia >= G_) continue;
            for (int dj = -ctx; dj <= ctx; dj++) {
                int jb = j - dj; if (jb < 0 || jb >= G_) continue;
                int ad = abs(di), aj = abs(dj);
                int cheb = ad > aj ? ad : aj;
                float coef = ldexpf(lr, -cheb);
                float4 t4 = ((const float4*)S)[(size_t)(jb * G_ + ia) * 128 + d4];
                nu.x += coef * t4.x; nu.y += coef * t4.y;
                nu.z += coef * t4.z; nu.w += coef * t4.w;
            }
        }
        float dn = denom[n];
        o.x = s.x + nu.x - s.x * dn;
        o.y = s.y + nu.y - s.y * dn;
        o.z = s.z + nu.z - s.z * dn;
        o.w = s.w + nu.w - s.w * dn;
    }
    ((float4*)out1)[i4] = o;
}

extern "C" void kernel_launch(void* const* d_in, const int* in_sizes, int n_in,
                              void* d_out, int out_size, void* d_ws, size_t ws_size,
                              hipStream_t stream) {
    const float* A   = (const float*)d_in[0];   // activations [B][D]
    const int*   lab = (const int*)d_in[1];     // labels [B]
    const float* W   = (const float*)d_in[2];   // som_vectors [G*G][D]
    const int*   cl  = (const int*)d_in[3];     // cell_labels [G*G]
    const float* cr  = (const float*)d_in[4];   // cell_reliability [G*G]
    const int*   ep  = (const int*)d_in[5];     // epoch
    const int*   me  = (const int*)d_in[6];     // max_epochs

    float* out0 = (float*)d_out;                // som_errors [B][D]
    float* out1 = out0 + (size_t)B_ * D_;       // new_som [G*G][D]

    const size_t MB = 1024 * 1024;
    uint8_t* w = (uint8_t*)d_ws;
    // phase 1 (score): split buffers occupy [0, 40 MB)
    _Float16* Ahi  = (_Float16*)(w);                    //  4 MB
    _Float16* Alo  = (_Float16*)(w + 4 * MB);           //  4 MB
    _Float16* Whi  = (_Float16*)(w + 8 * MB);           // 16 MB
    _Float16* Wlo  = (_Float16*)(w + 24 * MB);          // 16 MB
    // phase 2 (update): S aliases the dead split region [0, 32 MB)
    float* S       = (float*)(w);                       // 32 MB (after score)
    float* pminv   = (float*)(w + 40 * MB);             //  2 MB
    int*   pmini   = (int*)  (w + 42 * MB);             //  2 MB
    float* pcminv  = (float*)(w + 44 * MB);             //  2 MB
    int*   pcmini  = (int*)  (w + 46 * MB);             //  2 MB
    float* wnorm   = (float*)(w + 48 * MB);             // 64 KB
    float* denom   = (float*)(w + 48 * MB + 64 * 1024); // 64 KB
    float* count   = (float*)(w + 48 * MB + 128 * 1024);// 64 KB
    float* sum_min = (float*)(w + 48 * MB + 192 * 1024);// 4 B

    hipMemsetAsync(sum_min, 0, sizeof(float), stream);

    split_kernel<<<(B_ * D_ / 4 + 255) / 256, 256, 0, stream>>>(A, Ahi, Alo, B_ * D_ / 4);
    prep_w_kernel<<<N_, 64, 0, stream>>>(W, Whi, Wlo, wnorm);

    dim3 sg(NT, B_ / 128);   // (128, 32)
    score_mfma_kernel<<<sg, 256, 0, stream>>>(Ahi, Alo, Whi, Wlo, wnorm, lab, cl,
                                              pminv, pmini, pcminv, pcmini);

    // split buffers are dead now; reuse as S (stream-ordered)
    hipMemsetAsync(S, 0, (size_t)N_ * D_ * sizeof(float), stream);
    hipMemsetAsync(count, 0, (size_t)N_ * sizeof(float), stream);

    reduce_kernel<<<B_, 128, 0, stream>>>(A, W, cr, pminv, pmini, pcminv, pcmini,
                                          sum_min, out0, S, count);

    denom_kernel<<<(N_ + 255) / 256, 256, 0, stream>>>(count, ep, me, denom);

    final_kernel<<<(N_ * D_ / 4 + 255) / 256, 256, 0, stream>>>(
        W, S, denom, sum_min, ep, me, out1);
}

// Round 5
// 383.244 us; speedup vs baseline: 1.7035x; 1.7035x over previous
//
#include <hip/hip_runtime.h>
#include <math.h>

#define B_ 4096
#define D_ 512
#define G_ 128
#define N_ (G_*G_)        // 16384
#define NT 128            // number of 128-wide n tiles
#define THR_ 0.95f
#define IMAX_ 0x7FFFFFFF

typedef float f32x4 __attribute__((ext_vector_type(4)));
typedef _Float16 half8 __attribute__((ext_vector_type(8)));

// ---------------- split fp32 -> f16 hi only ----------------
__global__ __launch_bounds__(256) void split_hi_kernel(const float* __restrict__ src,
                                                       _Float16* __restrict__ hi, int n4) {
    int i = blockIdx.x * 256 + threadIdx.x;
    if (i >= n4) return;
    float4 v = ((const float4*)src)[i];
    float vv[4] = {v.x, v.y, v.z, v.w};
    union { _Float16 h[4]; uint64_t u64; } H;
    #pragma unroll
    for (int j = 0; j < 4; j++) H.h[j] = (_Float16)vv[j];
    ((uint64_t*)hi)[i] = H.u64;
}

// ---------------- fused W split(hi) + wnorm; 4 rows per 256-thread block ----------------
__global__ __launch_bounds__(256) void prep_w_kernel(const float* __restrict__ W,
                                                     _Float16* __restrict__ hi,
                                                     float* __restrict__ wnorm) {
    int n = blockIdx.x * 4 + (threadIdx.x >> 6);
    int t = threadIdx.x & 63;
    const float* row = W + (size_t)n * D_;
    float4 a = ((const float4*)row)[t];
    float4 b = ((const float4*)row)[t + 64];
    float av[4] = {a.x, a.y, a.z, a.w}, bv[4] = {b.x, b.y, b.z, b.w};
    union { _Float16 h[4]; uint64_t u64; } Ha, Hb;
    #pragma unroll
    for (int j = 0; j < 4; j++) { Ha.h[j] = (_Float16)av[j]; Hb.h[j] = (_Float16)bv[j]; }
    ((uint64_t*)(hi + (size_t)n * D_))[t]       = Ha.u64;
    ((uint64_t*)(hi + (size_t)n * D_ + 256))[t] = Hb.u64;
    float s = a.x*a.x + a.y*a.y + a.z*a.z + a.w*a.w
            + b.x*b.x + b.y*b.y + b.z*b.z + b.w*b.w;
    #pragma unroll
    for (int off = 32; off > 0; off >>= 1) s += __shfl_down(s, off, 64);
    if (t == 0) wnorm[n] = s;
}

// ---------------- MFMA score GEMM (pure f16) + fused per-tile argmin ----------------
// score = wnorm[n] - 2 * dot_f16(x, w)  (x_norm added per-row later; argmin-invariant).
// Round-3 staging (A+W tiles in LDS, dbuf, 1 barrier/iter) + round-4 XOR swizzle:
// writer at slot s=lane&3 of row r stores global chunk s^((r>>1)&3); reader of
// chunk q at row R uses slot q^((R>>1)&3) -> 2-way bank aliasing only (free).
__global__ __launch_bounds__(256) void score_mfma_kernel(
    const _Float16* __restrict__ Ah, const _Float16* __restrict__ Wh,
    const float* __restrict__ wnorm,
    const int* __restrict__ labels, const int* __restrict__ clabels,
    float* __restrict__ pminv, int* __restrict__ pmini,
    float* __restrict__ pcminv, int* __restrict__ pcmini)
{
    __shared__ __align__(16) char smem[32768];   // 2 x (As 8KB + Bs 8KB)

    const int tid  = threadIdx.x;
    const int lane = tid & 63;
    const int wave = tid >> 6;
    const int wm = wave >> 1, wn = wave & 1;   // 2x2 wave grid, 64x64 per wave
    const int m0 = blockIdx.y * 128;
    const int n0 = blockIdx.x * 128;
    const int c = lane & 15, quad = lane >> 4;

    // staging offsets: source k-chunk XOR-swizzled, LDS dest lane-contiguous
    unsigned offA[2], offW[2]; int offL[2];
    {
        int srow = wave * 16 + (lane >> 2);
        int sq = ((lane & 3) ^ ((lane >> 3) & 3)) * 8;
        #pragma unroll
        for (int r2 = 0; r2 < 2; r2++) {
            int row = r2 * 64 + srow;              // 0..127, each exactly once
            offA[r2] = (unsigned)(m0 + row) * D_ + sq;
            offW[r2] = (unsigned)(n0 + row) * D_ + sq;
            offL[r2] = row * 32 + (lane & 3) * 8;  // byte = waveBase + lane*16
        }
    }
    const int rpos = (quad ^ ((c >> 1) & 3)) * 8;  // reader swizzled slot (elements)

    f32x4 acc[4][4];
    #pragma unroll
    for (int i = 0; i < 4; i++)
        #pragma unroll
        for (int j = 0; j < 4; j++)
            acc[i][j] = (f32x4){0.f, 0.f, 0.f, 0.f};

    // prologue: stage chunk 0 into buf 0
    {
        _Float16* As = (_Float16*)smem;
        _Float16* Bs = (_Float16*)(smem + 8192);
        #pragma unroll
        for (int r2 = 0; r2 < 2; r2++) {
            __builtin_amdgcn_global_load_lds(
                (const __attribute__((address_space(1))) void*)(Ah + offA[r2]),
                (__attribute__((address_space(3))) void*)(As + offL[r2]), 16, 0, 0);
            __builtin_amdgcn_global_load_lds(
                (const __attribute__((address_space(1))) void*)(Wh + offW[r2]),
                (__attribute__((address_space(3))) void*)(Bs + offL[r2]), 16, 0, 0);
        }
    }

    #pragma unroll
    for (int t = 0; t < 16; t++) {
        const int p = t & 1, np = p ^ 1;
        __syncthreads();   // publishes buf p; drain has ~1 full iter of slack
        if (t < 15) {
            const int k1 = (t + 1) * 32;
            _Float16* As = (_Float16*)(smem + (np << 14));
            _Float16* Bs = (_Float16*)(smem + (np << 14) + 8192);
            #pragma unroll
            for (int r2 = 0; r2 < 2; r2++) {
                __builtin_amdgcn_global_load_lds(
                    (const __attribute__((address_space(1))) void*)(Ah + offA[r2] + k1),
                    (__attribute__((address_space(3))) void*)(As + offL[r2]), 16, 0, 0);
                __builtin_amdgcn_global_load_lds(
                    (const __attribute__((address_space(1))) void*)(Wh + offW[r2] + k1),
                    (__attribute__((address_space(3))) void*)(Bs + offL[r2]), 16, 0, 0);
            }
        }
        const _Float16* As = (const _Float16*)(smem + (p << 14));
        const _Float16* Bs = (const _Float16*)(smem + (p << 14) + 8192);
        half8 af[4], bf[4];
        #pragma unroll
        for (int i = 0; i < 4; i++) {
            af[i] = *(const half8*)&As[(wm * 64 + i * 16 + c) * 32 + rpos];
            bf[i] = *(const half8*)&Bs[(wn * 64 + i * 16 + c) * 32 + rpos];
        }
        #pragma unroll
        for (int i = 0; i < 4; i++)
            #pragma unroll
            for (int j = 0; j < 4; j++)
                acc[i][j] = __builtin_amdgcn_mfma_f32_16x16x32_f16(af[i], bf[j], acc[i][j], 0, 0, 0);
    }
    __syncthreads();   // done with tiles; reuse smem for reduction staging

    // per-lane epilogue: score s = wnorm[n] - 2*acc; argmin over (ni, c)
    float wnl[4]; int cll[4];
    #pragma unroll
    for (int ni = 0; ni < 4; ni++) {
        int n = n0 + wn * 64 + ni * 16 + c;
        wnl[ni] = wnorm[n];
        cll[ni] = clabels[n];
    }

    float* redv = (float*)smem;                 // [2][128]
    int*   redi = (int*)(smem + 1024);          // [2][128]
    float* rcv  = (float*)(smem + 2048);        // [2][128]
    int*   rci  = (int*)(smem + 3072);          // [2][128]

    #pragma unroll
    for (int mi = 0; mi < 4; mi++) {
        #pragma unroll
        for (int r = 0; r < 4; r++) {
            int rowg = wm * 64 + mi * 16 + quad * 4 + r;   // 0..127 in block
            int lb = labels[m0 + rowg];
            float bv = INFINITY; int bn = IMAX_;
            float cv = INFINITY; int cn = IMAX_;
            #pragma unroll
            for (int ni = 0; ni < 4; ni++) {
                float s = fmaf(-2.f, acc[mi][ni][r], wnl[ni]);
                int n = n0 + wn * 64 + ni * 16 + c;
                if (s < bv || (s == bv && n < bn)) { bv = s; bn = n; }
                float cs = (cll[ni] == lb) ? s : INFINITY;
                if (cs < cv || (cs == cv && n < cn)) { cv = cs; cn = n; }
            }
            #pragma unroll
            for (int off = 1; off < 16; off <<= 1) {   // butterfly over c
                float ov = __shfl_xor(bv, off, 64); int on = __shfl_xor(bn, off, 64);
                if (ov < bv || (ov == bv && on < bn)) { bv = ov; bn = on; }
                float ocv = __shfl_xor(cv, off, 64); int ocn = __shfl_xor(cn, off, 64);
                if (ocv < cv || (ocv == cv && ocn < cn)) { cv = ocv; cn = ocn; }
            }
            if (c == 0) {
                redv[wn * 128 + rowg] = bv; redi[wn * 128 + rowg] = bn;
                rcv [wn * 128 + rowg] = cv; rci [wn * 128 + rowg] = cn;
            }
        }
    }
    __syncthreads();
    if (tid < 128) {
        float bv = redv[tid];      int bn = redi[tid];
        float ov = redv[128 + tid]; int on = redi[128 + tid];
        if (ov < bv || (ov == bv && on < bn)) { bv = ov; bn = on; }
        float cv = rcv[tid];       int cn = rci[tid];
        float ocv = rcv[128 + tid]; int ocn = rci[128 + tid];
        if (ocv < cv || (ocv == cv && ocn < cn)) { cv = ocv; cn = ocn; }
        size_t pp = (size_t)(m0 + tid) * NT + blockIdx.x;
        pminv[pp] = bv; pmini[pp] = bn; pcminv[pp] = cv; pcmini[pp] = cn;
    }
}

// ---------------- reduce partials per row; emit bmu, sum(min_dists), som_errors ----------------
__global__ __launch_bounds__(128) void reduce_kernel(
    const float* __restrict__ A, const float* __restrict__ W,
    const float* __restrict__ crel,
    const float* __restrict__ pminv, const int* __restrict__ pmini,
    const float* __restrict__ pcminv, const int* __restrict__ pcmini,
    int* __restrict__ bmu, float* __restrict__ sum_min, float* __restrict__ out0)
{
    int b = blockIdx.x, t = threadIdx.x;
    __shared__ float sv[128]; __shared__ int si[128];
    __shared__ float scv[128]; __shared__ int sci[128];
    __shared__ float xs[128];
    __shared__ int   cbmu_s;

    size_t p = (size_t)b * NT + t;
    sv[t] = pminv[p]; si[t] = pmini[p]; scv[t] = pcminv[p]; sci[t] = pcmini[p];

    float4 x4 = ((const float4*)(A + (size_t)b * D_))[t];
    xs[t] = x4.x*x4.x + x4.y*x4.y + x4.z*x4.z + x4.w*x4.w;
    __syncthreads();
    for (int s = 64; s > 0; s >>= 1) {
        if (t < s) {
            float v = sv[t+s]; int idx = si[t+s];
            if (v < sv[t] || (v == sv[t] && idx < si[t])) { sv[t] = v; si[t] = idx; }
            v = scv[t+s]; idx = sci[t+s];
            if (v < scv[t] || (v == scv[t] && idx < sci[t])) { scv[t] = v; sci[t] = idx; }
            xs[t] += xs[t+s];
        }
        __syncthreads();
    }
    if (t == 0) {
        bmu[b] = si[0];
        float md = xs[0] + sv[0];
        if (md < 0.f) md = 0.f;
        atomicAdd(sum_min, md);
        cbmu_s = sci[0];
    }
    __syncthreads();
    int cb = cbmu_s;
    float r = crel[cb] / 100.0f;
    float val = (r >= THR_) ? 1.0f : 0.0f;
    float sc = 0.01f * r * val;
    float4 w4 = ((const float4*)(W + (size_t)cb * D_))[t];
    float4 o;
    o.x = sc * (w4.x - x4.x); o.y = sc * (w4.y - x4.y);
    o.z = sc * (w4.z - x4.z); o.w = sc * (w4.w - x4.w);
    ((float4*)(out0 + (size_t)b * D_))[t] = o;
}

// ---------------- per-BMU accumulate: S[bmu] += A[b], count[bmu] += 1 ----------------
__global__ __launch_bounds__(512) void scatter1_kernel(
    const float* __restrict__ A, const int* __restrict__ bmu,
    float* S, float* count)
{
    int b = blockIdx.x, d = threadIdx.x;
    int bm = bmu[b];
    float x = A[(size_t)b * D_ + d];
    atomicAdd(&S[(size_t)bm * D_ + d], x);
    if (d == 0) atomicAdd(&count[bm], 1.0f);
}

// ---------------- denom via Chebyshev stencil over counts ----------------
__global__ __launch_bounds__(256) void denom_kernel(
    const float* __restrict__ count,
    const int* __restrict__ epoch_p, const int* __restrict__ maxep_p,
    float* __restrict__ denom)
{
    int n = blockIdx.x * 256 + threadIdx.x;
    if (n >= N_) return;
    int ep = epoch_p[0], me = maxep_p[0];
    float progress = (me > 0) ? (float)(me - ep) / (float)me : 0.f;
    progress = fminf(fmaxf(progress, 0.f), 1.f);
    float p2 = progress * progress;
    int ctx = (int)(p2 * p2 * 2.0f);
    float lr = 0.05f + progress * 0.15f;

    int i = n / G_, j = n % G_;
    float s = 0.f;
    for (int di = -ctx; di <= ctx; di++) {
        int ia = i - di; if (ia < 0 || ia >= G_) continue;
        for (int dj = -ctx; dj <= ctx; dj++) {
            int jb = j - dj; if (jb < 0 || jb >= G_) continue;
            int ad = abs(di), aj = abs(dj);
            int cheb = ad > aj ? ad : aj;
            s += ldexpf(lr, -cheb) * count[jb * G_ + ia];
        }
    }
    denom[n] = s;
}

// ---------------- final: out1 = som + stencil(S) - som*denom (gated) ----------------
__global__ __launch_bounds__(256) void final_kernel(
    const float* __restrict__ som, const float* __restrict__ S,
    const float* __restrict__ denom, const float* __restrict__ sum_min,
    const int* __restrict__ epoch_p, const int* __restrict__ maxep_p,
    float* __restrict__ out1)
{
    size_t i4 = (size_t)blockIdx.x * 256 + threadIdx.x;
    if (i4 >= (size_t)N_ * D_ / 4) return;
    int n = (int)(i4 >> 7);          // 128 float4 per cell row
    int d4 = (int)(i4 & 127);
    float4 s = ((const float4*)som)[i4];
    bool gate = sum_min[0] > 1e-4f * (float)B_;   // mean(min_dists) > 1e-4
    float4 o = s;
    if (gate) {
        int ep = epoch_p[0], me = maxep_p[0];
        float progress = (me > 0) ? (float)(me - ep) / (float)me : 0.f;
        progress = fminf(fmaxf(progress, 0.f), 1.f);
        float p2 = progress * progress;
        int ctx = (int)(p2 * p2 * 2.0f);
        float lr = 0.05f + progress * 0.15f;

        int i = n / G_, j = n % G_;
        float4 nu = {0.f, 0.f, 0.f, 0.f};
        for (int di = -ctx; di <= ctx; di++) {
            int ia = i - di; if (ia < 0 || ia >= G_) continue;
            for (int dj = -ctx; dj <= ctx; dj++) {
                int jb = j - dj; if (jb < 0 || jb >= G_) continue;
                int ad = abs(di), aj = abs(dj);
                int cheb = ad > aj ? ad : aj;
                float coef = ldexpf(lr, -cheb);
                float4 t4 = ((const float4*)S)[(size_t)(jb * G_ + ia) * 128 + d4];
                nu.x += coef * t4.x; nu.y += coef * t4.y;
                nu.z += coef * t4.z; nu.w += coef * t4.w;
            }
        }
        float dn = denom[n];
        o.x = s.x + nu.x - s.x * dn;
        o.y = s.y + nu.y - s.y * dn;
        o.z = s.z + nu.z - s.z * dn;
        o.w = s.w + nu.w - s.w * dn;
    }
    ((float4*)out1)[i4] = o;
}

extern "C" void kernel_launch(void* const* d_in, const int* in_sizes, int n_in,
                              void* d_out, int out_size, void* d_ws, size_t ws_size,
                              hipStream_t stream) {
    const float* A   = (const float*)d_in[0];   // activations [B][D]
    const int*   lab = (const int*)d_in[1];     // labels [B]
    const float* W   = (const float*)d_in[2];   // som_vectors [G*G][D]
    const int*   cl  = (const int*)d_in[3];     // cell_labels [G*G]
    const float* cr  = (const float*)d_in[4];   // cell_reliability [G*G]
    const int*   ep  = (const int*)d_in[5];     // epoch
    const int*   me  = (const int*)d_in[6];     // max_epochs

    float* out0 = (float*)d_out;                // som_errors [B][D]
    float* out1 = out0 + (size_t)B_ * D_;       // new_som [G*G][D]

    const size_t MB = 1024 * 1024;
    uint8_t* w = (uint8_t*)d_ws;
    // phase 1 (score): f16-hi buffers occupy [0, 20 MB)
    _Float16* Ahi  = (_Float16*)(w);                    //  4 MB
    _Float16* Whi  = (_Float16*)(w + 4 * MB);           // 16 MB
    // phase 2 (update): S aliases the dead split region [0, 32 MB)
    float* S       = (float*)(w);                       // 32 MB (after score)
    float* pminv   = (float*)(w + 32 * MB);             //  2 MB
    int*   pmini   = (int*)  (w + 34 * MB);             //  2 MB
    float* pcminv  = (float*)(w + 36 * MB);             //  2 MB
    int*   pcmini  = (int*)  (w + 38 * MB);             //  2 MB
    float* wnorm   = (float*)(w + 40 * MB);             // 64 KB
    float* denom   = (float*)(w + 40 * MB + 64 * 1024); // 64 KB
    float* count   = (float*)(w + 40 * MB + 128 * 1024);// 64 KB
    int*   bmu     = (int*)  (w + 40 * MB + 192 * 1024);// 64 KB
    float* sum_min = (float*)(w + 40 * MB + 256 * 1024);// 4 B

    hipMemsetAsync(sum_min, 0, sizeof(float), stream);

    split_hi_kernel<<<(B_ * D_ / 4 + 255) / 256, 256, 0, stream>>>(A, Ahi, B_ * D_ / 4);
    prep_w_kernel<<<N_ / 4, 256, 0, stream>>>(W, Whi, wnorm);

    dim3 sg(NT, B_ / 128);   // (128, 32)
    score_mfma_kernel<<<sg, 256, 0, stream>>>(Ahi, Whi, wnorm, lab, cl,
                                              pminv, pmini, pcminv, pcmini);

    reduce_kernel<<<B_, 128, 0, stream>>>(A, W, cr, pminv, pmini, pcminv, pcmini,
                                          bmu, sum_min, out0);

    // f16 buffers are dead now; reuse as S (stream-ordered)
    hipMemsetAsync(S, 0, (size_t)N_ * D_ * sizeof(float), stream);
    hipMemsetAsync(count, 0, (size_t)N_ * sizeof(float), stream);

    scatter1_kernel<<<B_, 512, 0, stream>>>(A, bmu, S, count);

    denom_kernel<<<(N_ + 255) / 256, 256, 0, stream>>>(count, ep, me, denom);

    final_kernel<<<(N_ * D_ / 4 + 255) / 256, 256, 0, stream>>>(
        W, S, denom, sum_min, ep, me, out1);
}